// Round 5
// baseline (280.231 us; speedup 1.0000x reference)
//
#include <hip/hip_runtime.h>
#include <math.h>

// Problem constants
#define BH 64      // (b=4) * (h=16) folded leading dim
#define NB 32      // buckets
#define BS 128     // bucket size
#define DHEAD 64   // head dim

typedef __attribute__((ext_vector_type(8))) short bf16x8;
typedef __attribute__((ext_vector_type(4))) float f32x4;

#define LDVT 128   // transposed V: Vt[d=64][k=128] ushorts, XOR-swizzled rows

// K' LDS-image (produced by mix, consumed by attn via global_load_lds):
// per bucket: [plane hi|lo][s=0..127][64 ushorts], granule-swizzled:
//   idx(s,d) = s*64 + (d ^ ((s&7)<<3))     (XOR on bits 3..5 = 16B granule)

// ---------------- threefry2x32 (JAX partitionable PRNG), key = (0, 42) ----------------
__device__ __forceinline__ unsigned rotl32(unsigned x, int d) {
    return (x << d) | (x >> (32 - d));
}

__device__ __forceinline__ void threefry2x32(unsigned k0, unsigned k1,
                                             unsigned& x0, unsigned& x1) {
    const unsigned ks0 = k0, ks1 = k1, ks2 = k0 ^ k1 ^ 0x1BD11BDAu;
    const int r0[4] = {13, 15, 26, 6};
    const int r1[4] = {17, 29, 16, 24};
    x0 += ks0; x1 += ks1;
    #pragma unroll
    for (int i = 0; i < 4; i++) { x0 += x1; x1 = rotl32(x1, r0[i]); x1 ^= x0; }
    x0 += ks1; x1 += ks2 + 1u;
    #pragma unroll
    for (int i = 0; i < 4; i++) { x0 += x1; x1 = rotl32(x1, r1[i]); x1 ^= x0; }
    x0 += ks2; x1 += ks0 + 2u;
    #pragma unroll
    for (int i = 0; i < 4; i++) { x0 += x1; x1 = rotl32(x1, r0[i]); x1 ^= x0; }
    x0 += ks0; x1 += ks1 + 3u;
    #pragma unroll
    for (int i = 0; i < 4; i++) { x0 += x1; x1 = rotl32(x1, r1[i]); x1 ^= x0; }
    x0 += ks1; x1 += ks2 + 4u;
    #pragma unroll
    for (int i = 0; i < 4; i++) { x0 += x1; x1 = rotl32(x1, r0[i]); x1 ^= x0; }
    x0 += ks2; x1 += ks0 + 5u;
}

__device__ __forceinline__ float jax_uniform_part(unsigned f) {
    unsigned x0 = 0u, x1 = f;
    threefry2x32(0u, 42u, x0, x1);
    unsigned bits = x0 ^ x1;
    return __uint_as_float((bits >> 9) | 0x3F800000u) - 1.0f;
}

__device__ __forceinline__ unsigned rn16(float x) {
    return (__float_as_uint(x) + 0x8000u) >> 16;
}

// ---------------- kernel 1: bucket key sums pl[bh][u][d] (unchanged R4) ----------------
__global__ void __launch_bounds__(256)
pl_kernel(const float* __restrict__ k, float* __restrict__ pl) {
    int blk = blockIdx.x;             // bh*32 + u
    int tid = threadIdx.x;
    int w = tid >> 6, l = tid & 63;
    int rcls = l >> 4, c4 = l & 15;
    const float4* base = (const float4*)(k + (size_t)blk * 8192);

    float4 acc = {0.f, 0.f, 0.f, 0.f};
    #pragma unroll
    for (int t = 0; t < 8; t++) {
        float4 x = base[(w * 32 + t * 4 + rcls) * 16 + c4];
        acc.x += x.x; acc.y += x.y; acc.z += x.z; acc.w += x.w;
    }
    #pragma unroll
    for (int off = 16; off < 64; off <<= 1) {
        acc.x += __shfl_xor(acc.x, off);
        acc.y += __shfl_xor(acc.y, off);
        acc.z += __shfl_xor(acc.z, off);
        acc.w += __shfl_xor(acc.w, off);
    }
    __shared__ float4 red[4][16];
    if (rcls == 0) red[w][c4] = acc;
    __syncthreads();
    if (tid < 64) {
        int g = tid >> 2, j = tid & 3;
        float s = ((const float*)&red[0][g])[j] + ((const float*)&red[1][g])[j]
                + ((const float*)&red[2][g])[j] + ((const float*)&red[3][g])[j];
        pl[blk * 64 + tid] = s;
    }
}

// ---------------- kernel 2: routing (unchanged R4) ----------------
__global__ void route_kernel(const float* __restrict__ pl, const float* __restrict__ Wk,
                             float* __restrict__ Rout) {
    int bh = blockIdx.x;            // 64 blocks
    int h = bh & 15;
    int tid = threadIdx.x;          // 1024 threads
    int i = tid >> 5, j = tid & 31;

    __shared__ float plS[NB * DHEAD];
    __shared__ float T[32 * 33];
    __shared__ float colL[32];

    for (int x = tid; x < NB * DHEAD; x += 1024) plS[x] = pl[bh * NB * DHEAD + x];
    __syncthreads();

    float acc = 0.f;
    #pragma unroll 8
    for (int d2 = 0; d2 < DHEAD; d2++)
        acc += plS[i * DHEAD + d2] * Wk[(h * DHEAD + d2) * NB + j];

    unsigned f = (unsigned)bh * 1024u + (unsigned)i * 32u + (unsigned)j;
    float u = jax_uniform_part(f);
    float g = -__logf(-__logf(u + 1e-6f) + 1e-6f);
    float val = (acc + g) / 0.75f;

    for (int it = 0; it < 5; it++) {
        float m = val;
        #pragma unroll
        for (int off = 1; off < 32; off <<= 1) m = fmaxf(m, __shfl_xor(m, off, 32));
        float s = __expf(val - m);
        #pragma unroll
        for (int off = 1; off < 32; off <<= 1) s += __shfl_xor(s, off, 32);
        val -= m + __logf(s);

        T[i * 33 + j] = val;
        __syncthreads();
        float tv = T[j * 33 + i];
        float m2 = tv;
        #pragma unroll
        for (int off = 1; off < 32; off <<= 1) m2 = fmaxf(m2, __shfl_xor(m2, off, 32));
        float s2 = __expf(tv - m2);
        #pragma unroll
        for (int off = 1; off < 32; off <<= 1) s2 += __shfl_xor(s2, off, 32);
        if (j == 0) colL[i] = m2 + __logf(s2);
        __syncthreads();
        val -= colL[j];
    }
    Rout[bh * 1024 + i * 32 + j] = __expf(val) + (i == j ? 1.0f : 0.0f);
}

// ---------------- kernel 3: K' = R' * K, split-bf16 LDS-image (unchanged R4) ----------------
__global__ void __launch_bounds__(256)
mix_kernel(const float* __restrict__ k, const float* __restrict__ Rp,
           unsigned short* __restrict__ khl) {
    __shared__ float X[32][260];
    int bh = blockIdx.x >> 5;       // 64 bh x 32 tiles
    int tile = blockIdx.x & 31;
    const size_t kbase = (size_t)bh * 262144;
    const int col0 = tile * 256;

    {   // stage: thread loads 8 float4 from row j = tid>>3
        int j = threadIdx.x >> 3;
        int cs = (threadIdx.x & 7) * 32;
        const float4* src = (const float4*)(k + kbase + (size_t)j * 8192 + col0 + cs);
        #pragma unroll
        for (int t = 0; t < 8; t++)
            *((float4*)&X[j][cs + 4 * t]) = src[t];
    }
    __syncthreads();

    const int col = threadIdx.x;
    float xv[32];
    #pragma unroll
    for (int j = 0; j < 32; j++) xv[j] = X[j][col];

    const float* Rb = Rp + bh * 1024;   // uniform -> s_load
    const int slot = col0 + col;        // flat index into bucket's [128][64]
    const int s = slot >> 6, d = slot & 63;
    const int idx = s * 64 + (d ^ ((s & 7) << 3));   // swizzled LDS-image index
    const bool even = (col & 1) == 0;

    #pragma unroll 4
    for (int i = 0; i < 32; i++) {
        float acc = 0.f;
        #pragma unroll
        for (int j = 0; j < 32; j++) acc = fmaf(Rb[i * 32 + j], xv[j], acc);
        unsigned kb = __float_as_uint(acc);
        unsigned hiu = kb >> 16;
        float rem = acc - __uint_as_float(kb & 0xFFFF0000u);
        unsigned lou = __float_as_uint(rem) >> 16;
        unsigned oh = (unsigned)__shfl_xor((int)hiu, 1);
        unsigned ol = (unsigned)__shfl_xor((int)lou, 1);
        if (even) {
            unsigned short* bp = khl + ((size_t)(bh * 32 + i) << 14);  // bucket base
            *(unsigned*)&bp[idx]        = hiu | (oh << 16);
            *(unsigned*)&bp[idx + 8192] = lou | (ol << 16);
        }
    }
}

// ---------------- kernel 4: attention, swapped-QK^T, P in registers ----------------
// S^T = K'.Q^T (same LDS/Q loads, swapped MFMA operands; A- and B-layouts share
// the lane map for 16x16).  Lane (quad,l15) then holds S^T[k=16tc+4quad+r][q=l15+16ti]
// => softmax row is in-lane: 31 ops + shfl_xor(16,32).  P normalized, packed bf16,
// rearranged to A-fragments via ds_bpermute (dual-gather + cndmask avoids
// runtime-indexed reg arrays).  V: global->reg early (T14), reg->LDS aliasing Kh
// after QK.  LDS 51200 -> 32768 B; P LDS round-trip and one barrier removed.
__global__ void __launch_bounds__(256, 4)
attn_mfma_kernel(const float* __restrict__ q, const unsigned short* __restrict__ khl,
                 const float* __restrict__ v, float* __restrict__ out) {
    __shared__ __align__(16) unsigned short smem[16384];   // 32768 B
    unsigned short* KhS = smem;            // [128][64] swizzled plane
    unsigned short* KlS = smem + 8192;     // [128][64] swizzled plane
    unsigned short* VtS = smem;            // [64][LDVT] swizzled, aliases KhS after QK

    const int tid = threadIdx.x;
    const int w = tid >> 6, lane = tid & 63;
    const int quad = lane >> 4, l15 = lane & 15;
    const int row0 = 32 * w;
    const size_t base = (size_t)blockIdx.x * (BS * DHEAD);

    // ---- async stage K' planes: 8 chunks x 4096 B, lane-linear ----
    {
        const char* src = (const char*)(khl + ((size_t)blockIdx.x << 14)) + tid * 16;
        char* dst = (char*)KhS + tid * 16;
        #pragma unroll
        for (int c = 0; c < 8; c++)
            __builtin_amdgcn_global_load_lds(
                (const __attribute__((address_space(1))) unsigned int*)(src + c * 4096),
                (__attribute__((address_space(3))) unsigned int*)(dst + c * 4096),
                16, 0, 0);
    }

    // ---- V: global -> packed bf16 regs (write to LDS deferred past QK) ----
    const int rp = tid >> 2;              // k row-pair 0..63
    const int c0v = (tid & 3) * 16;       // d column group
    unsigned vt[16];
    {
        const float* v0 = v + base + (size_t)(2 * rp) * DHEAD + c0v;
        const float* v1 = v0 + DHEAD;
        #pragma unroll
        for (int x = 0; x < 4; x++) {
            float4 a = ((const float4*)v0)[x];
            float4 b = ((const float4*)v1)[x];
            float fa[4] = {a.x, a.y, a.z, a.w};
            float fb[4] = {b.x, b.y, b.z, b.w};
            #pragma unroll
            for (int y = 0; y < 4; y++)
                vt[4 * x + y] = rn16(fa[y]) | (rn16(fb[y]) << 16);
        }
    }

    // ---- Q A/B-fragments (scaled by 1/8 exactly, split hi/lo bf16) ----
    bf16x8 qh[2][2], ql[2][2];
    #pragma unroll
    for (int ti = 0; ti < 2; ti++) {
        #pragma unroll
        for (int kk = 0; kk < 2; kk++) {
            const float* qp = q + base + (size_t)(row0 + 16 * ti + l15) * DHEAD
                              + kk * 32 + quad * 8;
            float4 a = ((const float4*)qp)[0];
            float4 b = ((const float4*)qp)[1];
            float f[8] = {a.x, a.y, a.z, a.w, b.x, b.y, b.z, b.w};
            #pragma unroll
            for (int j = 0; j < 8; j++) {
                float qs = f[j] * 0.125f;                 // exact (pow2)
                unsigned bits = __float_as_uint(qs);
                unsigned short hi = (unsigned short)(bits >> 16);
                float rem = qs - __uint_as_float(bits & 0xFFFF0000u);
                unsigned short lo = (unsigned short)(__float_as_uint(rem) >> 16);
                qh[ti][kk][j] = (short)hi;
                ql[ti][kk][j] = (short)lo;
            }
        }
    }
    __syncthreads();   // barrier 1: K planes in LDS (vmcnt(0) drain)

    // ---- S^T = K' Qs^T : acc[ti][tc][r] = S[q=l15+16ti][k=16tc+4quad+r] ----
    f32x4 acc[2][8];
    #pragma unroll
    for (int ti = 0; ti < 2; ti++)
        #pragma unroll
        for (int tc = 0; tc < 8; tc++)
            acc[ti][tc] = (f32x4){0.f, 0.f, 0.f, 0.f};

    #pragma unroll
    for (int tc = 0; tc < 8; tc++) {
        const int jrow = 16 * tc + l15;          // k-row of the K' fragment
        const int swzk = (jrow & 7) << 3;
        const int rbase = jrow * 64;
        bf16x8 kh0 = *(const bf16x8*)&KhS[rbase + ((quad * 8 + 0)  ^ swzk)];
        bf16x8 kh1 = *(const bf16x8*)&KhS[rbase + ((quad * 8 + 32) ^ swzk)];
        bf16x8 kl0 = *(const bf16x8*)&KlS[rbase + ((quad * 8 + 0)  ^ swzk)];
        bf16x8 kl1 = *(const bf16x8*)&KlS[rbase + ((quad * 8 + 32) ^ swzk)];
        __builtin_amdgcn_s_setprio(1);
        #pragma unroll
        for (int ti = 0; ti < 2; ti++) {
            f32x4 c = acc[ti][tc];
            c = __builtin_amdgcn_mfma_f32_16x16x32_bf16(kh0, qh[ti][0], c, 0, 0, 0);
            c = __builtin_amdgcn_mfma_f32_16x16x32_bf16(kh1, qh[ti][1], c, 0, 0, 0);
            c = __builtin_amdgcn_mfma_f32_16x16x32_bf16(kh0, ql[ti][0], c, 0, 0, 0);
            c = __builtin_amdgcn_mfma_f32_16x16x32_bf16(kh1, ql[ti][1], c, 0, 0, 0);
            c = __builtin_amdgcn_mfma_f32_16x16x32_bf16(kl0, qh[ti][0], c, 0, 0, 0);
            c = __builtin_amdgcn_mfma_f32_16x16x32_bf16(kl1, qh[ti][1], c, 0, 0, 0);
            acc[ti][tc] = c;
        }
        __builtin_amdgcn_s_setprio(0);
    }

    // ---- softmax: rows fully in-lane (over tc,r) + quad reduce ----
    unsigned pkA[2][8], pkB[2][8];
    #pragma unroll
    for (int ti = 0; ti < 2; ti++) {
        float m = acc[ti][0][0];
        #pragma unroll
        for (int tc = 0; tc < 8; tc++)
            #pragma unroll
            for (int r = 0; r < 4; r++)
                m = fmaxf(m, acc[ti][tc][r]);
        m = fmaxf(m, __shfl_xor(m, 16));
        m = fmaxf(m, __shfl_xor(m, 32));
        float s = 0.f;
        #pragma unroll
        for (int tc = 0; tc < 8; tc++)
            #pragma unroll
            for (int r = 0; r < 4; r++) {
                float p = __expf(acc[ti][tc][r] - m);
                acc[ti][tc][r] = p;
                s += p;
            }
        s += __shfl_xor(s, 16);
        s += __shfl_xor(s, 32);
        float inv = 1.0f / s;
        // pre-normalize and pack to bf16 pairs: pkA = (r0,r1), pkB = (r2,r3)
        #pragma unroll
        for (int tc = 0; tc < 8; tc++) {
            pkA[ti][tc] = rn16(acc[ti][tc][0] * inv) | (rn16(acc[ti][tc][1] * inv) << 16);
            pkB[ti][tc] = rn16(acc[ti][tc][2] * inv) | (rn16(acc[ti][tc][3] * inv) << 16);
        }
    }

    __syncthreads();   // barrier 2: all waves done reading Kh/Kl

    // ---- write Vt (from regs) over KhS region, swizzled ----
    {
        #pragma unroll
        for (int x = 0; x < 4; x++)
            #pragma unroll
            for (int y = 0; y < 4; y++) {
                int c = c0v + 4 * x + y;
                unsigned swz = ((unsigned)((c ^ (c >> 4)) & 15)) << 3;
                unsigned idx = (unsigned)c * LDVT + (((unsigned)(2 * rp)) ^ swz);
                *(unsigned*)&VtS[idx] = vt[4 * x + y];
            }
    }
    __syncthreads();   // barrier 3: Vt ready

    // ---- O = P V : P A-fragments via dual ds_bpermute + quad-select ----
    f32x4 oacc[2][4];
    #pragma unroll
    for (int ti = 0; ti < 2; ti++)
        #pragma unroll
        for (int tc = 0; tc < 4; tc++)
            oacc[ti][tc] = (f32x4){0.f, 0.f, 0.f, 0.f};

    const int a0 = ((((2 * quad) & 3) * 16 + l15) << 2);       // src lane qs0
    const int a1 = ((((2 * quad + 1) & 3) * 16 + l15) << 2);   // src lane qs1
    const bool hiTile = (quad >> 1) != 0;                      // tc_s = 2kc + (quad>>1)

    #pragma unroll
    for (int kc = 0; kc < 4; kc++) {
        bf16x8 pa[2];
        #pragma unroll
        for (int ti = 0; ti < 2; ti++) {
            unsigned uA0 = (unsigned)__builtin_amdgcn_ds_bpermute(a0, (int)pkA[ti][2 * kc]);
            unsigned uA1 = (unsigned)__builtin_amdgcn_ds_bpermute(a0, (int)pkA[ti][2 * kc + 1]);
            unsigned uB0 = (unsigned)__builtin_amdgcn_ds_bpermute(a0, (int)pkB[ti][2 * kc]);
            unsigned uB1 = (unsigned)__builtin_amdgcn_ds_bpermute(a0, (int)pkB[ti][2 * kc + 1]);
            unsigned vA0 = (unsigned)__builtin_amdgcn_ds_bpermute(a1, (int)pkA[ti][2 * kc]);
            unsigned vA1 = (unsigned)__builtin_amdgcn_ds_bpermute(a1, (int)pkA[ti][2 * kc + 1]);
            unsigned vB0 = (unsigned)__builtin_amdgcn_ds_bpermute(a1, (int)pkB[ti][2 * kc]);
            unsigned vB1 = (unsigned)__builtin_amdgcn_ds_bpermute(a1, (int)pkB[ti][2 * kc + 1]);
            union { unsigned u[4]; bf16x8 v; } pu;
            pu.u[0] = hiTile ? uA1 : uA0;
            pu.u[1] = hiTile ? uB1 : uB0;
            pu.u[2] = hiTile ? vA1 : vA0;
            pu.u[3] = hiTile ? vB1 : vB0;
            pa[ti] = pu.v;
        }
        __builtin_amdgcn_s_setprio(1);
        #pragma unroll
        for (int tc = 0; tc < 4; tc++) {
            unsigned n = (unsigned)(16 * tc + l15);
            unsigned swz = ((n ^ (n >> 4)) & 15u) << 3;
            unsigned idx = n * LDVT + (((unsigned)(kc * 32 + quad * 8)) ^ swz);
            bf16x8 vb = *(const bf16x8*)&VtS[idx];
            #pragma unroll
            for (int ti = 0; ti < 2; ti++)
                oacc[ti][tc] = __builtin_amdgcn_mfma_f32_16x16x32_bf16(pa[ti], vb, oacc[ti][tc], 0, 0, 0);
        }
        __builtin_amdgcn_s_setprio(0);
    }

    // ---- epilogue: store (P was pre-normalized) ----
    #pragma unroll
    for (int ti = 0; ti < 2; ti++)
        #pragma unroll
        for (int tc = 0; tc < 4; tc++)
            #pragma unroll
            for (int r = 0; r < 4; r++) {
                int orow = row0 + 16 * ti + quad * 4 + r;
                out[base + (size_t)orow * DHEAD + 16 * tc + l15] = oacc[ti][tc][r];
            }
}

extern "C" void kernel_launch(void* const* d_in, const int* in_sizes, int n_in,
                              void* d_out, int out_size, void* d_ws, size_t ws_size,
                              hipStream_t stream) {
    const float* q  = (const float*)d_in[0];
    const float* k  = (const float*)d_in[1];
    const float* v  = (const float*)d_in[2];
    const float* Wk = (const float*)d_in[3];
    float* out = (float*)d_out;

    // ws layout: khl split-bf16 K' image (2048 buckets x 16384 ushorts = 64 MiB)
    //            | pl (131072 f) | R' (65536 f)
    unsigned short* khl = (unsigned short*)d_ws;
    float* pl = (float*)(khl + (size_t)33554432);
    float* R  = pl + (size_t)131072;

    pl_kernel<<<dim3(BH * NB), dim3(256), 0, stream>>>(k, pl);
    route_kernel<<<dim3(BH), dim3(1024), 0, stream>>>(pl, Wk, R);
    mix_kernel<<<dim3(BH * NB), dim3(256), 0, stream>>>(k, R, khl);
    attn_mfma_kernel<<<dim3(BH * NB), dim3(256), 0, stream>>>(q, khl, v, out);
}